// Round 3
// baseline (7027.387 us; speedup 1.0000x reference)
//
#include <hip/hip_runtime.h>
#include <hip/hip_bf16.h>

// Problem constants (B,T,D,L) = (16, 4096, 256, 512)
#define RNN_B 16
#define RNN_T 4096
#define RNN_D 256
#define RNN_L 512

typedef __fp16   fp16x2 __attribute__((ext_vector_type(2)));  // builtin-compatible
typedef _Float16 f16x8  __attribute__((ext_vector_type(8)));  // MFMA fragment
typedef float    f32x4  __attribute__((ext_vector_type(4)));

__device__ __forceinline__ unsigned pk2(float a, float b) {
    auto h = __builtin_amdgcn_cvt_pkrtz(a, b);   // __fp16 ext_vector(2)
    return __builtin_bit_cast(unsigned, h);
}

__device__ __forceinline__ float dot2u(unsigned wa, unsigned hb, float c) {
#if defined(__has_builtin) && __has_builtin(__builtin_amdgcn_fdot2)
    return __builtin_amdgcn_fdot2(__builtin_bit_cast(fp16x2, wa),
                                  __builtin_bit_cast(fp16x2, hb), c, false);
#else
    fp16x2 a = __builtin_bit_cast(fp16x2, wa), b = __builtin_bit_cast(fp16x2, hb);
    return c + (float)a[0] * (float)b[0] + (float)a[1] * (float)b[1];
#endif
}

// ---------------------------------------------------------------------------
// K1: Z[t,b,l] = sum_k x[b,t,k] * Wi[l,k] + bm[l], written as FLOAT32 into the
// hidden_states region of d_out (K2 reads it and overwrites with h in place).
// Tile 64(M) x 64(N), K-step 32, 4 waves, MFMA f32_16x16x32_f16.
// ---------------------------------------------------------------------------
__global__ __launch_bounds__(256) void proj_kernel(
        const float* __restrict__ x, const float* __restrict__ Wi,
        const float* __restrict__ bm, float* __restrict__ Zout) {
    __shared__ __align__(16) _Float16 As[64 * 40];  // +8 pad: 80B row stride
    __shared__ __align__(16) _Float16 Bs[64 * 40];

    const int bid = blockIdx.x;
    const int mt = bid >> 3, nt = bid & 7;
    const int mBase = mt * 64, nBase = nt * 64;
    const int tid = threadIdx.x;
    const int w = tid >> 6, l = tid & 63;

    // staging assignment: thread -> (row in tile, 8-wide k chunk)
    const int srow = tid >> 2, skc = (tid & 3) * 8;
    const int m = mBase + srow;
    const int bb = m & 15, tt = m >> 4;
    const float* ax = x + ((size_t)bb * RNN_T + tt) * RNN_D + skc;
    const float* bw = Wi + (size_t)(nBase + srow) * RNN_D + skc;

    f32x4 acc[4] = {};

#pragma unroll 1
    for (int k0 = 0; k0 < RNN_D; k0 += 32) {
        __syncthreads();
        float4 a0 = *(const float4*)(ax + k0);
        float4 a1 = *(const float4*)(ax + k0 + 4);
        float4 b0 = *(const float4*)(bw + k0);
        float4 b1 = *(const float4*)(bw + k0 + 4);
        uint4 ua = {pk2(a0.x, a0.y), pk2(a0.z, a0.w), pk2(a1.x, a1.y), pk2(a1.z, a1.w)};
        uint4 ub = {pk2(b0.x, b0.y), pk2(b0.z, b0.w), pk2(b1.x, b1.y), pk2(b1.z, b1.w)};
        *(uint4*)(As + srow * 40 + skc) = ua;
        *(uint4*)(Bs + srow * 40 + skc) = ub;
        __syncthreads();

        f16x8 af = *(const f16x8*)(As + (w * 16 + (l & 15)) * 40 + (l >> 4) * 8);
#pragma unroll
        for (int n = 0; n < 4; ++n) {
            f16x8 bf = *(const f16x8*)(Bs + (n * 16 + (l & 15)) * 40 + (l >> 4) * 8);
            acc[n] = __builtin_amdgcn_mfma_f32_16x16x32_f16(af, bf, acc[n], 0, 0, 0);
        }
    }

    // epilogue: C/D layout col = lane&15, row = (lane>>4)*4 + reg
    const int colL = l & 15, rg = l >> 4;
#pragma unroll
    for (int n = 0; n < 4; ++n) {
        const int col = nBase + n * 16 + colL;
        const float bias = bm[col];
#pragma unroll
        for (int q = 0; q < 4; ++q) {
            const int row = mBase + w * 16 + rg * 4 + q;
            Zout[(size_t)row * RNN_L + col] = acc[n][q] + bias;
        }
    }
}

// ---------------------------------------------------------------------------
// K2: sequential scan. 16 blocks (one per batch), 512 threads (8 waves).
// Lane (w,l) owns output channel j = w*64+l = tid. Wm row j lives on-CU:
//   k in [0,384): 192 packed f16x2 in VGPRs
//   k in [384,512): 64 packed f16x2 in LDS (128 KB total, b128-readable)
// h is double-buffered in LDS as f16x2 pairs; one barrier per step.
// ---------------------------------------------------------------------------
#define KRP 192   // reg-resident f16x2 pairs per lane (k < 384)
#define K2_LDS_BYTES (131072 + 2048 + 64)

__global__ __launch_bounds__(512) void rnn_scan(
        const float* __restrict__ Wm, const float* __restrict__ Wo,
        float* __restrict__ out_o, float* __restrict__ out_h) {
    extern __shared__ __align__(16) char smem[];
    uint4* wlds = (uint4*)smem;                          // [8*16][64] uint4 = 128 KB
    unsigned* hbuf = (unsigned*)(smem + 131072);         // [2][256] f16x2 pairs
    float* opart = (float*)(smem + 131072 + 2048);       // [2][8]

    const int b = blockIdx.x;
    const int tid = threadIdx.x, w = tid >> 6, l = tid & 63, j = tid;

    // ---- prologue: load & pack Wm row j ----
    unsigned wreg[KRP];
    const float4* wrow = (const float4*)(Wm + (size_t)j * RNN_L);
#pragma unroll
    for (int c = 0; c < 6; ++c) {
#pragma unroll
        for (int gi = 0; gi < 16; ++gi) {
            const int g = c * 16 + gi;
            float4 v = wrow[g];
            wreg[2 * g]     = pk2(v.x, v.y);
            wreg[2 * g + 1] = pk2(v.z, v.w);
        }
        __builtin_amdgcn_sched_barrier(0);  // cap in-flight loads (reg pressure)
    }
#pragma unroll
    for (int g = 0; g < 16; ++g) {
        float4 v0 = wrow[96 + 2 * g];
        float4 v1 = wrow[97 + 2 * g];
        uint4 u = {pk2(v0.x, v0.y), pk2(v0.z, v0.w), pk2(v1.x, v1.y), pk2(v1.z, v1.w)};
        wlds[(w * 16 + g) * 64 + l] = u;
    }
    const float wo = Wo[j];
    hbuf[tid] = 0;  // 512 entries: zeroes both h buffers (h0 = 0)
    __syncthreads();

    float* zh = out_h + (size_t)b * RNN_L + j;  // holds Z now, h later (f32)

#pragma unroll 1
    for (int t = 0; t < RNN_T; ++t) {
        const int cur = t & 1;
        float z = zh[(size_t)t * (RNN_B * RNN_L)];
        const uint4* hb4 = (const uint4*)(hbuf + cur * 256);

        float acc = 0.f;
#pragma unroll
        for (int g = 0; g < 48; ++g) {   // k in [0,384): weights from VGPRs
            uint4 hh = hb4[g];           // broadcast read, all lanes same addr
            acc = dot2u(wreg[4 * g + 0], hh.x, acc);
            acc = dot2u(wreg[4 * g + 1], hh.y, acc);
            acc = dot2u(wreg[4 * g + 2], hh.z, acc);
            acc = dot2u(wreg[4 * g + 3], hh.w, acc);
        }
#pragma unroll
        for (int g = 0; g < 16; ++g) {   // k in [384,512): weights from LDS
            uint4 ww = wlds[(w * 16 + g) * 64 + l];  // lane-stride 16B, conflict-free
            uint4 hh = hb4[48 + g];
            acc = dot2u(ww.x, hh.x, acc);
            acc = dot2u(ww.y, hh.y, acc);
            acc = dot2u(ww.z, hh.z, acc);
            acc = dot2u(ww.w, hh.w, acc);
        }

        const float pre = z + acc;
        const float hn = 1.f / (1.f + __expf(-pre));

        // pack (h[j], h[j+1]) into next h buffer (even lanes)
        const float hnb = __shfl_down(hn, 1);
        if (!(l & 1)) hbuf[(cur ^ 1) * 256 + (j >> 1)] = pk2(hn, hnb);

        // o partial: wave-level reduce of hn * Wo[j]
        float po = hn * wo;
#pragma unroll
        for (int off = 1; off < 64; off <<= 1) po += __shfl_xor(po, off);
        if (l == 0) opart[cur * 8 + w] = po;

        __syncthreads();

        // global h store AFTER barrier: barrier's vmcnt drain never waits on it
        zh[(size_t)t * (RNN_B * RNN_L)] = hn;

        if (tid == 0) {
            float o = 0.f;
#pragma unroll
            for (int w2 = 0; w2 < 8; ++w2) o += opart[cur * 8 + w2];
            out_o[t * RNN_B + b] = o;
        }
    }
}

// ---------------------------------------------------------------------------
extern "C" void kernel_launch(void* const* d_in, const int* in_sizes, int n_in,
                              void* d_out, int out_size, void* d_ws, size_t ws_size,
                              hipStream_t stream) {
    const float* x  = (const float*)d_in[0];   // [16,4096,256]
    const float* Wi = (const float*)d_in[1];   // [512,256]
    const float* Wm = (const float*)d_in[2];   // [512,512]
    const float* bm = (const float*)d_in[3];   // [512]
    const float* Wo = (const float*)d_in[4];   // [1,512]

    float* out_o = (float*)d_out;                 // [T*B] = 65536 floats
    float* out_h = out_o + (RNN_T * RNN_B);       // [T*B*L] floats

    // K1: Z = x @ Wi^T + bm  -> hidden_states region (scratch, overwritten by K2)
    proj_kernel<<<dim3((RNN_T * RNN_B / 64) * (RNN_L / 64)), dim3(256), 0, stream>>>(
        x, Wi, bm, out_h);

    // K2: sequential recurrence, one WG per batch, 130 KB dynamic LDS
    (void)hipFuncSetAttribute(reinterpret_cast<const void*>(rnn_scan),
                              hipFuncAttributeMaxDynamicSharedMemorySize, K2_LDS_BYTES);
    rnn_scan<<<dim3(RNN_B), dim3(512), K2_LDS_BYTES, stream>>>(Wm, Wo, out_o, out_h);
}

// Round 4
// 5911.193 us; speedup vs baseline: 1.1888x; 1.1888x over previous
//
#include <hip/hip_runtime.h>
#include <hip/hip_bf16.h>

// Problem constants (B,T,D,L) = (16, 4096, 256, 512)
#define RNN_B 16
#define RNN_T 4096
#define RNN_D 256
#define RNN_L 512

typedef __fp16   fp16x2 __attribute__((ext_vector_type(2)));  // builtin-compatible
typedef _Float16 f16x8  __attribute__((ext_vector_type(8)));  // MFMA fragment
typedef float    f32x4  __attribute__((ext_vector_type(4)));

__device__ __forceinline__ unsigned pk2(float a, float b) {
    auto h = __builtin_amdgcn_cvt_pkrtz(a, b);   // __fp16 ext_vector(2)
    return __builtin_bit_cast(unsigned, h);
}

__device__ __forceinline__ float dot2u(unsigned wa, unsigned hb, float c) {
#if defined(__has_builtin) && __has_builtin(__builtin_amdgcn_fdot2)
    return __builtin_amdgcn_fdot2(__builtin_bit_cast(fp16x2, wa),
                                  __builtin_bit_cast(fp16x2, hb), c, false);
#else
    fp16x2 a = __builtin_bit_cast(fp16x2, wa), b = __builtin_bit_cast(fp16x2, hb);
    return c + (float)a[0] * (float)b[0] + (float)a[1] * (float)b[1];
#endif
}

// ---------------------------------------------------------------------------
// K1: Z[t,b,l] = sum_k x[b,t,k] * Wi[l,k] + bm[l], written as FLOAT32 into the
// hidden_states region of d_out (K2 reads it and overwrites with h in place).
// Tile 64(M) x 64(N), K-step 32, 4 waves, MFMA f32_16x16x32_f16.
// ---------------------------------------------------------------------------
__global__ __launch_bounds__(256) void proj_kernel(
        const float* __restrict__ x, const float* __restrict__ Wi,
        const float* __restrict__ bm, float* __restrict__ Zout) {
    __shared__ __align__(16) _Float16 As[64 * 40];  // +8 pad: 80B row stride
    __shared__ __align__(16) _Float16 Bs[64 * 40];

    const int bid = blockIdx.x;
    const int mt = bid >> 3, nt = bid & 7;
    const int mBase = mt * 64, nBase = nt * 64;
    const int tid = threadIdx.x;
    const int w = tid >> 6, l = tid & 63;

    // staging assignment: thread -> (row in tile, 8-wide k chunk)
    const int srow = tid >> 2, skc = (tid & 3) * 8;
    const int m = mBase + srow;
    const int bb = m & 15, tt = m >> 4;
    const float* ax = x + ((size_t)bb * RNN_T + tt) * RNN_D + skc;
    const float* bw = Wi + (size_t)(nBase + srow) * RNN_D + skc;

    f32x4 acc[4] = {};

#pragma unroll 1
    for (int k0 = 0; k0 < RNN_D; k0 += 32) {
        __syncthreads();
        float4 a0 = *(const float4*)(ax + k0);
        float4 a1 = *(const float4*)(ax + k0 + 4);
        float4 b0 = *(const float4*)(bw + k0);
        float4 b1 = *(const float4*)(bw + k0 + 4);
        uint4 ua = {pk2(a0.x, a0.y), pk2(a0.z, a0.w), pk2(a1.x, a1.y), pk2(a1.z, a1.w)};
        uint4 ub = {pk2(b0.x, b0.y), pk2(b0.z, b0.w), pk2(b1.x, b1.y), pk2(b1.z, b1.w)};
        *(uint4*)(As + srow * 40 + skc) = ua;
        *(uint4*)(Bs + srow * 40 + skc) = ub;
        __syncthreads();

        f16x8 af = *(const f16x8*)(As + (w * 16 + (l & 15)) * 40 + (l >> 4) * 8);
#pragma unroll
        for (int n = 0; n < 4; ++n) {
            f16x8 bf = *(const f16x8*)(Bs + (n * 16 + (l & 15)) * 40 + (l >> 4) * 8);
            acc[n] = __builtin_amdgcn_mfma_f32_16x16x32_f16(af, bf, acc[n], 0, 0, 0);
        }
    }

    // epilogue: C/D layout col = lane&15, row = (lane>>4)*4 + reg
    const int colL = l & 15, rg = l >> 4;
#pragma unroll
    for (int n = 0; n < 4; ++n) {
        const int col = nBase + n * 16 + colL;
        const float bias = bm[col];
#pragma unroll
        for (int q = 0; q < 4; ++q) {
            const int row = mBase + w * 16 + rg * 4 + q;
            Zout[(size_t)row * RNN_L + col] = acc[n][q] + bias;
        }
    }
}

// ---------------------------------------------------------------------------
// K2: sequential scan. 16 blocks (one per batch), 512 threads (8 waves),
// __launch_bounds__(512,2): 2 waves/SIMD -> 256-VGPR budget (dynamic LDS hid
// the real occupancy from the compiler; R3 spilled wreg at 128 VGPRs).
// Lane owns channel j = tid. Wm row j on-CU:
//   k in [0,416): 208 packed f16x2 in VGPRs
//   k in [416,512): 12 uint4 per channel in LDS (96 KB)
// h double-buffered in LDS as f16x2; one barrier per step. No o-work here.
// ---------------------------------------------------------------------------
#define KRP 208                     // reg-resident f16x2 pairs per lane
#define WG  12                      // uint4 weight groups per channel in LDS
#define WLDS_BYTES (WG * 512 * 16)  // 98304
#define K2_LDS_BYTES (WLDS_BYTES + 2048 + 64)

__global__ __launch_bounds__(512, 2) void rnn_scan(
        const float* __restrict__ Wm,
        float* __restrict__ out_h) {
    extern __shared__ __align__(16) char smem[];
    uint4* wlds = (uint4*)smem;                              // [WG][512] uint4
    unsigned* hbuf = (unsigned*)(smem + WLDS_BYTES);         // [2][256] f16x2

    const int b = blockIdx.x;
    const int tid = threadIdx.x, j = tid;

    // ---- prologue: load & pack Wm row j ----
    unsigned wreg[KRP];
    const float4* wrow = (const float4*)(Wm + (size_t)j * RNN_L);
#pragma unroll
    for (int c = 0; c < 13; ++c) {               // 13 chunks x 8 float4 = 104
#pragma unroll
        for (int gi = 0; gi < 8; ++gi) {
            const int g = c * 8 + gi;
            float4 v = wrow[g];
            wreg[2 * g]     = pk2(v.x, v.y);
            wreg[2 * g + 1] = pk2(v.z, v.w);
        }
        __builtin_amdgcn_sched_barrier(0);       // cap in-flight loads
    }
#pragma unroll
    for (int g = 0; g < WG; ++g) {               // k in [416,512) -> LDS
        float4 v0 = wrow[104 + 2 * g];
        float4 v1 = wrow[105 + 2 * g];
        uint4 u = {pk2(v0.x, v0.y), pk2(v0.z, v0.w), pk2(v1.x, v1.y), pk2(v1.z, v1.w)};
        wlds[g * 512 + j] = u;
    }
    hbuf[tid] = 0;  // 512 entries: zeroes both h buffers (h0 = 0)
    __syncthreads();

    float* zh = out_h + (size_t)b * RNN_L + j;  // holds Z now, h later (f32)

#pragma unroll 1
    for (int t = 0; t < RNN_T; ++t) {
        const int cur = t & 1;
        float z = zh[(size_t)t * (RNN_B * RNN_L)];
        const uint4* hb4 = (const uint4*)(hbuf + cur * 256);

        float acc = 0.f;
#pragma unroll
        for (int g = 0; g < KRP / 4; ++g) {      // k in [0,416): weights in VGPRs
            uint4 hh = hb4[g];                   // broadcast read
            acc = dot2u(wreg[4 * g + 0], hh.x, acc);
            acc = dot2u(wreg[4 * g + 1], hh.y, acc);
            acc = dot2u(wreg[4 * g + 2], hh.z, acc);
            acc = dot2u(wreg[4 * g + 3], hh.w, acc);
        }
#pragma unroll
        for (int g = 0; g < WG; ++g) {           // k in [416,512): weights in LDS
            uint4 ww = wlds[g * 512 + j];        // lane-stride 16B, conflict-free
            uint4 hh = hb4[KRP / 4 + g];
            acc = dot2u(ww.x, hh.x, acc);
            acc = dot2u(ww.y, hh.y, acc);
            acc = dot2u(ww.z, hh.z, acc);
            acc = dot2u(ww.w, hh.w, acc);
        }

        const float pre = z + acc;
        const float hn = 1.f / (1.f + __expf(-pre));

        // pack (h[j], h[j+1]) into next h buffer (even lanes)
        const float hnb = __shfl_down(hn, 1);
        if (!(tid & 1)) hbuf[(cur ^ 1) * 256 + (j >> 1)] = pk2(hn, hnb);

        __syncthreads();

        // global h store AFTER barrier: this step's barrier never waits on it
        zh[(size_t)t * (RNN_B * RNN_L)] = hn;
    }
}

// ---------------------------------------------------------------------------
// K3: o[t,b] = sum_j Wo[j] * h[t,b,j]. Memory-bound re-read of h (~134 MB).
// One wave per (t,b) row; 4 rows per 256-thread block.
// ---------------------------------------------------------------------------
__global__ __launch_bounds__(256) void out_proj(
        const float* __restrict__ Wo, const float* __restrict__ h,
        float* __restrict__ o) {
    const int l = threadIdx.x & 63;
    const int r = blockIdx.x * 4 + (threadIdx.x >> 6);   // r = t*B + b
    const float4* hp = (const float4*)(h + (size_t)r * RNN_L);
    const float4* wp = (const float4*)Wo;
    float4 a0 = hp[l * 2], a1 = hp[l * 2 + 1];
    float4 b0 = wp[l * 2], b1 = wp[l * 2 + 1];
    float s = a0.x * b0.x + a0.y * b0.y + a0.z * b0.z + a0.w * b0.w
            + a1.x * b1.x + a1.y * b1.y + a1.z * b1.z + a1.w * b1.w;
#pragma unroll
    for (int off = 1; off < 64; off <<= 1) s += __shfl_xor(s, off);
    if (l == 0) o[r] = s;
}

// ---------------------------------------------------------------------------
extern "C" void kernel_launch(void* const* d_in, const int* in_sizes, int n_in,
                              void* d_out, int out_size, void* d_ws, size_t ws_size,
                              hipStream_t stream) {
    const float* x  = (const float*)d_in[0];   // [16,4096,256]
    const float* Wi = (const float*)d_in[1];   // [512,256]
    const float* Wm = (const float*)d_in[2];   // [512,512]
    const float* bm = (const float*)d_in[3];   // [512]
    const float* Wo = (const float*)d_in[4];   // [1,512]

    float* out_o = (float*)d_out;                 // [T*B] = 65536 floats
    float* out_h = out_o + (RNN_T * RNN_B);       // [T*B*L] floats

    // K1: Z = x @ Wi^T + bm  -> hidden_states region (scratch, overwritten by K2)
    proj_kernel<<<dim3((RNN_T * RNN_B / 64) * (RNN_L / 64)), dim3(256), 0, stream>>>(
        x, Wi, bm, out_h);

    // K2: sequential recurrence, one WG per batch, ~98 KB dynamic LDS
    (void)hipFuncSetAttribute(reinterpret_cast<const void*>(rnn_scan),
                              hipFuncAttributeMaxDynamicSharedMemorySize, K2_LDS_BYTES);
    rnn_scan<<<dim3(RNN_B), dim3(512), K2_LDS_BYTES, stream>>>(Wm, out_h);

    // K3: o = h . Wo
    out_proj<<<dim3(RNN_T * RNN_B / 4), dim3(256), 0, stream>>>(Wo, out_h, out_o);
}

// Round 5
// 5902.460 us; speedup vs baseline: 1.1906x; 1.0015x over previous
//
#include <hip/hip_runtime.h>
#include <hip/hip_bf16.h>

// Problem constants (B,T,D,L) = (16, 4096, 256, 512)
#define RNN_B 16
#define RNN_T 4096
#define RNN_D 256
#define RNN_L 512

typedef __fp16   fp16x2 __attribute__((ext_vector_type(2)));  // builtin-compatible
typedef _Float16 f16x8  __attribute__((ext_vector_type(8)));  // MFMA fragment
typedef float    f32x4  __attribute__((ext_vector_type(4)));

__device__ __forceinline__ unsigned pk2(float a, float b) {
    auto h = __builtin_amdgcn_cvt_pkrtz(a, b);   // __fp16 ext_vector(2)
    return __builtin_bit_cast(unsigned, h);
}

__device__ __forceinline__ float dot2u(unsigned wa, unsigned hb, float c) {
#if defined(__has_builtin) && __has_builtin(__builtin_amdgcn_fdot2)
    return __builtin_amdgcn_fdot2(__builtin_bit_cast(fp16x2, wa),
                                  __builtin_bit_cast(fp16x2, hb), c, false);
#else
    fp16x2 a = __builtin_bit_cast(fp16x2, wa), b = __builtin_bit_cast(fp16x2, hb);
    return c + (float)a[0] * (float)b[0] + (float)a[1] * (float)b[1];
#endif
}

// ---------------------------------------------------------------------------
// K1: Z[t,b,l] = sum_k x[b,t,k] * Wi[l,k] + bm[l], written as FLOAT32 into the
// hidden_states region of d_out (K2 reads it and overwrites with h in place).
// Tile 64(M) x 64(N), K-step 32, 4 waves, MFMA f32_16x16x32_f16.
// ---------------------------------------------------------------------------
__global__ __launch_bounds__(256) void proj_kernel(
        const float* __restrict__ x, const float* __restrict__ Wi,
        const float* __restrict__ bm, float* __restrict__ Zout) {
    __shared__ __align__(16) _Float16 As[64 * 40];  // +8 pad: 80B row stride
    __shared__ __align__(16) _Float16 Bs[64 * 40];

    const int bid = blockIdx.x;
    const int mt = bid >> 3, nt = bid & 7;
    const int mBase = mt * 64, nBase = nt * 64;
    const int tid = threadIdx.x;
    const int w = tid >> 6, l = tid & 63;

    // staging assignment: thread -> (row in tile, 8-wide k chunk)
    const int srow = tid >> 2, skc = (tid & 3) * 8;
    const int m = mBase + srow;
    const int bb = m & 15, tt = m >> 4;
    const float* ax = x + ((size_t)bb * RNN_T + tt) * RNN_D + skc;
    const float* bw = Wi + (size_t)(nBase + srow) * RNN_D + skc;

    f32x4 acc[4] = {};

#pragma unroll 1
    for (int k0 = 0; k0 < RNN_D; k0 += 32) {
        __syncthreads();
        float4 a0 = *(const float4*)(ax + k0);
        float4 a1 = *(const float4*)(ax + k0 + 4);
        float4 b0 = *(const float4*)(bw + k0);
        float4 b1 = *(const float4*)(bw + k0 + 4);
        uint4 ua = {pk2(a0.x, a0.y), pk2(a0.z, a0.w), pk2(a1.x, a1.y), pk2(a1.z, a1.w)};
        uint4 ub = {pk2(b0.x, b0.y), pk2(b0.z, b0.w), pk2(b1.x, b1.y), pk2(b1.z, b1.w)};
        *(uint4*)(As + srow * 40 + skc) = ua;
        *(uint4*)(Bs + srow * 40 + skc) = ub;
        __syncthreads();

        f16x8 af = *(const f16x8*)(As + (w * 16 + (l & 15)) * 40 + (l >> 4) * 8);
#pragma unroll
        for (int n = 0; n < 4; ++n) {
            f16x8 bf = *(const f16x8*)(Bs + (n * 16 + (l & 15)) * 40 + (l >> 4) * 8);
            acc[n] = __builtin_amdgcn_mfma_f32_16x16x32_f16(af, bf, acc[n], 0, 0, 0);
        }
    }

    // epilogue: C/D layout col = lane&15, row = (lane>>4)*4 + reg
    const int colL = l & 15, rg = l >> 4;
#pragma unroll
    for (int n = 0; n < 4; ++n) {
        const int col = nBase + n * 16 + colL;
        const float bias = bm[col];
#pragma unroll
        for (int q = 0; q < 4; ++q) {
            const int row = mBase + w * 16 + rg * 4 + q;
            Zout[(size_t)row * RNN_L + col] = acc[n][q] + bias;
        }
    }
}

// ---------------------------------------------------------------------------
// K2: sequential scan. 16 blocks (one per batch), 512 threads (8 waves).
// amdgpu_waves_per_eu(2,2): 2 waves/SIMD -> 256-VGPR/wave budget. (R4 showed
// __launch_bounds__(512,2) gave a 128-reg budget -> wreg spilled to scratch.)
// Lane owns channel j = tid. Wm row j on-CU:
//   k in [0,416): 208 packed f16x2 in VGPRs
//   k in [416,512): 12 uint4 per channel in LDS (96 KB)
// h double-buffered in LDS as f16x2; one barrier per step. z prefetched 1 step.
// ---------------------------------------------------------------------------
#define KRP 208                     // reg-resident f16x2 pairs per lane
#define WG  12                      // uint4 weight groups per channel in LDS
#define WLDS_BYTES (WG * 512 * 16)  // 98304
#define K2_LDS_BYTES (WLDS_BYTES + 2048 + 64)

__global__ void
__attribute__((amdgpu_flat_work_group_size(512, 512)))
__attribute__((amdgpu_waves_per_eu(2, 2)))
rnn_scan(const float* __restrict__ Wm, float* __restrict__ out_h) {
    extern __shared__ __align__(16) char smem[];
    uint4* wlds = (uint4*)smem;                              // [WG][512] uint4
    unsigned* hbuf = (unsigned*)(smem + WLDS_BYTES);         // [2][256] f16x2

    const int b = blockIdx.x;
    const int tid = threadIdx.x, j = tid;

    // ---- prologue: load & pack Wm row j ----
    unsigned wreg[KRP];
    const float4* wrow = (const float4*)(Wm + (size_t)j * RNN_L);
#pragma unroll
    for (int c = 0; c < 13; ++c) {               // 13 chunks x 8 float4 = 104
#pragma unroll
        for (int gi = 0; gi < 8; ++gi) {
            const int g = c * 8 + gi;
            float4 v = wrow[g];
            wreg[2 * g]     = pk2(v.x, v.y);
            wreg[2 * g + 1] = pk2(v.z, v.w);
        }
        __builtin_amdgcn_sched_barrier(0);       // cap in-flight loads
    }
#pragma unroll
    for (int g = 0; g < WG; ++g) {               // k in [416,512) -> LDS
        float4 v0 = wrow[104 + 2 * g];
        float4 v1 = wrow[105 + 2 * g];
        uint4 u = {pk2(v0.x, v0.y), pk2(v0.z, v0.w), pk2(v1.x, v1.y), pk2(v1.z, v1.w)};
        wlds[g * 512 + j] = u;
    }
    hbuf[tid] = 0;  // 512 entries: zeroes both h buffers (h0 = 0)
    __syncthreads();

    float* zh = out_h + (size_t)b * RNN_L + j;  // holds Z now, h later (f32)
    float z = zh[0];                            // prefetched z for t=0

#pragma unroll 1
    for (int t = 0; t < RNN_T; ++t) {
        const int cur = t & 1;
        // prefetch z for t+1 (clamped; issues a full step before its use)
        const int tn = (t < RNN_T - 1) ? t + 1 : t;
        const float znext = zh[(size_t)tn * (RNN_B * RNN_L)];
        const uint4* hb4 = (const uint4*)(hbuf + cur * 256);

        float acc = 0.f;
#pragma unroll
        for (int g = 0; g < KRP / 4; ++g) {      // k in [0,416): weights in VGPRs
            uint4 hh = hb4[g];                   // broadcast read
            acc = dot2u(wreg[4 * g + 0], hh.x, acc);
            acc = dot2u(wreg[4 * g + 1], hh.y, acc);
            acc = dot2u(wreg[4 * g + 2], hh.z, acc);
            acc = dot2u(wreg[4 * g + 3], hh.w, acc);
        }
#pragma unroll
        for (int g = 0; g < WG; ++g) {           // k in [416,512): weights in LDS
            uint4 ww = wlds[g * 512 + j];        // lane-stride 16B, conflict-free
            uint4 hh = hb4[KRP / 4 + g];
            acc = dot2u(ww.x, hh.x, acc);
            acc = dot2u(ww.y, hh.y, acc);
            acc = dot2u(ww.z, hh.z, acc);
            acc = dot2u(ww.w, hh.w, acc);
        }

        const float pre = z + acc;
        const float hn = 1.f / (1.f + __expf(-pre));

        // pack (h[j], h[j+1]) into next h buffer (even lanes)
        const float hnb = __shfl_down(hn, 1);
        if (!(tid & 1)) hbuf[(cur ^ 1) * 256 + (j >> 1)] = pk2(hn, hnb);

        __syncthreads();

        // global h store AFTER barrier: this step's barrier never waits on it
        zh[(size_t)t * (RNN_B * RNN_L)] = hn;
        z = znext;
    }
}

// ---------------------------------------------------------------------------
// K3: o[t,b] = sum_j Wo[j] * h[t,b,j]. Memory-bound re-read of h (~134 MB).
// One wave per (t,b) row; 4 rows per 256-thread block.
// ---------------------------------------------------------------------------
__global__ __launch_bounds__(256) void out_proj(
        const float* __restrict__ Wo, const float* __restrict__ h,
        float* __restrict__ o) {
    const int l = threadIdx.x & 63;
    const int r = blockIdx.x * 4 + (threadIdx.x >> 6);   // r = t*B + b
    const float4* hp = (const float4*)(h + (size_t)r * RNN_L);
    const float4* wp = (const float4*)Wo;
    float4 a0 = hp[l * 2], a1 = hp[l * 2 + 1];
    float4 b0 = wp[l * 2], b1 = wp[l * 2 + 1];
    float s = a0.x * b0.x + a0.y * b0.y + a0.z * b0.z + a0.w * b0.w
            + a1.x * b1.x + a1.y * b1.y + a1.z * b1.z + a1.w * b1.w;
#pragma unroll
    for (int off = 1; off < 64; off <<= 1) s += __shfl_xor(s, off);
    if (l == 0) o[r] = s;
}

// ---------------------------------------------------------------------------
extern "C" void kernel_launch(void* const* d_in, const int* in_sizes, int n_in,
                              void* d_out, int out_size, void* d_ws, size_t ws_size,
                              hipStream_t stream) {
    const float* x  = (const float*)d_in[0];   // [16,4096,256]
    const float* Wi = (const float*)d_in[1];   // [512,256]
    const float* Wm = (const float*)d_in[2];   // [512,512]
    const float* bm = (const float*)d_in[3];   // [512]
    const float* Wo = (const float*)d_in[4];   // [1,512]

    float* out_o = (float*)d_out;                 // [T*B] = 65536 floats
    float* out_h = out_o + (RNN_T * RNN_B);       // [T*B*L] floats

    // K1: Z = x @ Wi^T + bm  -> hidden_states region (scratch, overwritten by K2)
    proj_kernel<<<dim3((RNN_T * RNN_B / 64) * (RNN_L / 64)), dim3(256), 0, stream>>>(
        x, Wi, bm, out_h);

    // K2: sequential recurrence, one WG per batch, ~98 KB dynamic LDS
    (void)hipFuncSetAttribute(reinterpret_cast<const void*>(rnn_scan),
                              hipFuncAttributeMaxDynamicSharedMemorySize, K2_LDS_BYTES);
    rnn_scan<<<dim3(RNN_B), dim3(512), K2_LDS_BYTES, stream>>>(Wm, out_h);

    // K3: o = h . Wo
    out_proj<<<dim3(RNN_T * RNN_B / 4), dim3(256), 0, stream>>>(Wo, out_h, out_o);
}

// Round 6
// 5881.126 us; speedup vs baseline: 1.1949x; 1.0036x over previous
//
#include <hip/hip_runtime.h>
#include <hip/hip_bf16.h>

// Problem constants (B,T,D,L) = (16, 4096, 256, 512)
#define RNN_B 16
#define RNN_T 4096
#define RNN_D 256
#define RNN_L 512

typedef __fp16   fp16x2 __attribute__((ext_vector_type(2)));  // builtin-compatible
typedef _Float16 f16x8  __attribute__((ext_vector_type(8)));  // MFMA fragment
typedef float    f32x4  __attribute__((ext_vector_type(4)));

__device__ __forceinline__ unsigned pk2(float a, float b) {
    auto h = __builtin_amdgcn_cvt_pkrtz(a, b);   // __fp16 ext_vector(2)
    return __builtin_bit_cast(unsigned, h);
}

__device__ __forceinline__ float dot2u(unsigned wa, unsigned hb, float c) {
#if defined(__has_builtin) && __has_builtin(__builtin_amdgcn_fdot2)
    return __builtin_amdgcn_fdot2(__builtin_bit_cast(fp16x2, wa),
                                  __builtin_bit_cast(fp16x2, hb), c, false);
#else
    fp16x2 a = __builtin_bit_cast(fp16x2, wa), b = __builtin_bit_cast(fp16x2, hb);
    return c + (float)a[0] * (float)b[0] + (float)a[1] * (float)b[1];
#endif
}

// ---------------------------------------------------------------------------
// K1: Z[t,b,l] = sum_k x[b,t,k] * Wi[l,k] + bm[l], written as FLOAT32 into the
// hidden_states region of d_out (K2 reads it and overwrites with h in place).
// Tile 64(M) x 64(N), K-step 32, 4 waves, MFMA f32_16x16x32_f16.
// ---------------------------------------------------------------------------
__global__ __launch_bounds__(256) void proj_kernel(
        const float* __restrict__ x, const float* __restrict__ Wi,
        const float* __restrict__ bm, float* __restrict__ Zout) {
    __shared__ __align__(16) _Float16 As[64 * 40];  // +8 pad: 80B row stride
    __shared__ __align__(16) _Float16 Bs[64 * 40];

    const int bid = blockIdx.x;
    const int mt = bid >> 3, nt = bid & 7;
    const int mBase = mt * 64, nBase = nt * 64;
    const int tid = threadIdx.x;
    const int w = tid >> 6, l = tid & 63;

    // staging assignment: thread -> (row in tile, 8-wide k chunk)
    const int srow = tid >> 2, skc = (tid & 3) * 8;
    const int m = mBase + srow;
    const int bb = m & 15, tt = m >> 4;
    const float* ax = x + ((size_t)bb * RNN_T + tt) * RNN_D + skc;
    const float* bw = Wi + (size_t)(nBase + srow) * RNN_D + skc;

    f32x4 acc[4] = {};

#pragma unroll 1
    for (int k0 = 0; k0 < RNN_D; k0 += 32) {
        __syncthreads();
        float4 a0 = *(const float4*)(ax + k0);
        float4 a1 = *(const float4*)(ax + k0 + 4);
        float4 b0 = *(const float4*)(bw + k0);
        float4 b1 = *(const float4*)(bw + k0 + 4);
        uint4 ua = {pk2(a0.x, a0.y), pk2(a0.z, a0.w), pk2(a1.x, a1.y), pk2(a1.z, a1.w)};
        uint4 ub = {pk2(b0.x, b0.y), pk2(b0.z, b0.w), pk2(b1.x, b1.y), pk2(b1.z, b1.w)};
        *(uint4*)(As + srow * 40 + skc) = ua;
        *(uint4*)(Bs + srow * 40 + skc) = ub;
        __syncthreads();

        f16x8 af = *(const f16x8*)(As + (w * 16 + (l & 15)) * 40 + (l >> 4) * 8);
#pragma unroll
        for (int n = 0; n < 4; ++n) {
            f16x8 bf = *(const f16x8*)(Bs + (n * 16 + (l & 15)) * 40 + (l >> 4) * 8);
            acc[n] = __builtin_amdgcn_mfma_f32_16x16x32_f16(af, bf, acc[n], 0, 0, 0);
        }
    }

    // epilogue: C/D layout col = lane&15, row = (lane>>4)*4 + reg
    const int colL = l & 15, rg = l >> 4;
#pragma unroll
    for (int n = 0; n < 4; ++n) {
        const int col = nBase + n * 16 + colL;
        const float bias = bm[col];
#pragma unroll
        for (int q = 0; q < 4; ++q) {
            const int row = mBase + w * 16 + rg * 4 + q;
            Zout[(size_t)row * RNN_L + col] = acc[n][q] + bias;
        }
    }
}

// ---------------------------------------------------------------------------
// K2: sequential scan. 16 blocks (one per batch), 512 threads (8 waves).
// amdgpu_waves_per_eu(2,2): 2 waves/SIMD -> 256-VGPR/wave budget.
// R4/R5 forensics: VGPR_Count stayed 120 under both budget attributes ->
// the mid-end SINKS the weight loads into the t-loop (remat). Fix: pin each
// wreg element with an empty `asm volatile("" : "+v")` after the prologue —
// an opaque VGPR-class def that cannot be rematerialized or AGPR-parked.
// Lane owns channel j = tid. Wm row j on-CU:
//   k in [0,416): 208 packed f16x2 in VGPRs (pinned)
//   k in [416,512): 12 uint4 per channel in LDS (96 KB)
// h double-buffered in LDS as f16x2; one barrier per step. z prefetched 1 step.
// ---------------------------------------------------------------------------
#define KRP 208                     // reg-resident f16x2 pairs per lane
#define WG  12                      // uint4 weight groups per channel in LDS
#define WLDS_BYTES (WG * 512 * 16)  // 98304
#define K2_LDS_BYTES (WLDS_BYTES + 2048 + 64)

__global__ void
__attribute__((amdgpu_flat_work_group_size(512, 512)))
__attribute__((amdgpu_waves_per_eu(2, 2)))
rnn_scan(const float* __restrict__ Wm, float* __restrict__ out_h) {
    extern __shared__ __align__(16) char smem[];
    uint4* wlds = (uint4*)smem;                              // [WG][512] uint4
    unsigned* hbuf = (unsigned*)(smem + WLDS_BYTES);         // [2][256] f16x2

    const int b = blockIdx.x;
    const int tid = threadIdx.x, j = tid;

    // ---- prologue: load & pack Wm row j ----
    unsigned wreg[KRP];
    const float4* wrow = (const float4*)(Wm + (size_t)j * RNN_L);
#pragma unroll
    for (int c = 0; c < 13; ++c) {               // 13 chunks x 8 float4 = 104
#pragma unroll
        for (int gi = 0; gi < 8; ++gi) {
            const int g = c * 8 + gi;
            float4 v = wrow[g];
            wreg[2 * g]     = pk2(v.x, v.y);
            wreg[2 * g + 1] = pk2(v.z, v.w);
        }
    }
    // Pin every weight word live in a VGPR: opaque def -> no remat, no sink,
    // no AGPR parking. Zero instructions emitted.
#pragma unroll
    for (int g = 0; g < KRP; ++g) {
        asm volatile("" : "+v"(wreg[g]));
    }
#pragma unroll
    for (int g = 0; g < WG; ++g) {               // k in [416,512) -> LDS
        float4 v0 = wrow[104 + 2 * g];
        float4 v1 = wrow[105 + 2 * g];
        uint4 u = {pk2(v0.x, v0.y), pk2(v0.z, v0.w), pk2(v1.x, v1.y), pk2(v1.z, v1.w)};
        wlds[g * 512 + j] = u;
    }
    hbuf[tid] = 0;  // 512 entries: zeroes both h buffers (h0 = 0)
    __syncthreads();

    float* zh = out_h + (size_t)b * RNN_L + j;  // holds Z now, h later (f32)
    float z = zh[0];                            // prefetched z for t=0

#pragma unroll 1
    for (int t = 0; t < RNN_T; ++t) {
        const int cur = t & 1;
        // prefetch z for t+1 (clamped; issues a full step before its use)
        const int tn = (t < RNN_T - 1) ? t + 1 : t;
        const float znext = zh[(size_t)tn * (RNN_B * RNN_L)];
        const uint4* hb4 = (const uint4*)(hbuf + cur * 256);

        float acc = 0.f;
#pragma unroll
        for (int g = 0; g < KRP / 4; ++g) {      // k in [0,416): weights in VGPRs
            uint4 hh = hb4[g];                   // broadcast read
            acc = dot2u(wreg[4 * g + 0], hh.x, acc);
            acc = dot2u(wreg[4 * g + 1], hh.y, acc);
            acc = dot2u(wreg[4 * g + 2], hh.z, acc);
            acc = dot2u(wreg[4 * g + 3], hh.w, acc);
        }
#pragma unroll
        for (int g = 0; g < WG; ++g) {           // k in [416,512): weights in LDS
            uint4 ww = wlds[g * 512 + j];        // lane-stride 16B, conflict-free
            uint4 hh = hb4[KRP / 4 + g];
            acc = dot2u(ww.x, hh.x, acc);
            acc = dot2u(ww.y, hh.y, acc);
            acc = dot2u(ww.z, hh.z, acc);
            acc = dot2u(ww.w, hh.w, acc);
        }

        const float pre = z + acc;
        const float hn = 1.f / (1.f + __expf(-pre));

        // pack (h[j], h[j+1]) into next h buffer (even lanes)
        const float hnb = __shfl_down(hn, 1);
        if (!(tid & 1)) hbuf[(cur ^ 1) * 256 + (j >> 1)] = pk2(hn, hnb);

        __syncthreads();

        // global h store AFTER barrier: this step's barrier never waits on it
        zh[(size_t)t * (RNN_B * RNN_L)] = hn;
        z = znext;
    }
}

// ---------------------------------------------------------------------------
// K3: o[t,b] = sum_j Wo[j] * h[t,b,j]. Memory-bound re-read of h (~134 MB).
// One wave per (t,b) row; 4 rows per 256-thread block.
// ---------------------------------------------------------------------------
__global__ __launch_bounds__(256) void out_proj(
        const float* __restrict__ Wo, const float* __restrict__ h,
        float* __restrict__ o) {
    const int l = threadIdx.x & 63;
    const int r = blockIdx.x * 4 + (threadIdx.x >> 6);   // r = t*B + b
    const float4* hp = (const float4*)(h + (size_t)r * RNN_L);
    const float4* wp = (const float4*)Wo;
    float4 a0 = hp[l * 2], a1 = hp[l * 2 + 1];
    float4 b0 = wp[l * 2], b1 = wp[l * 2 + 1];
    float s = a0.x * b0.x + a0.y * b0.y + a0.z * b0.z + a0.w * b0.w
            + a1.x * b1.x + a1.y * b1.y + a1.z * b1.z + a1.w * b1.w;
#pragma unroll
    for (int off = 1; off < 64; off <<= 1) s += __shfl_xor(s, off);
    if (l == 0) o[r] = s;
}

// ---------------------------------------------------------------------------
extern "C" void kernel_launch(void* const* d_in, const int* in_sizes, int n_in,
                              void* d_out, int out_size, void* d_ws, size_t ws_size,
                              hipStream_t stream) {
    const float* x  = (const float*)d_in[0];   // [16,4096,256]
    const float* Wi = (const float*)d_in[1];   // [512,256]
    const float* Wm = (const float*)d_in[2];   // [512,512]
    const float* bm = (const float*)d_in[3];   // [512]
    const float* Wo = (const float*)d_in[4];   // [1,512]

    float* out_o = (float*)d_out;                 // [T*B] = 65536 floats
    float* out_h = out_o + (RNN_T * RNN_B);       // [T*B*L] floats

    // K1: Z = x @ Wi^T + bm  -> hidden_states region (scratch, overwritten by K2)
    proj_kernel<<<dim3((RNN_T * RNN_B / 64) * (RNN_L / 64)), dim3(256), 0, stream>>>(
        x, Wi, bm, out_h);

    // K2: sequential recurrence, one WG per batch, ~98 KB dynamic LDS
    (void)hipFuncSetAttribute(reinterpret_cast<const void*>(rnn_scan),
                              hipFuncAttributeMaxDynamicSharedMemorySize, K2_LDS_BYTES);
    rnn_scan<<<dim3(RNN_B), dim3(512), K2_LDS_BYTES, stream>>>(Wm, out_h);

    // K3: o = h . Wo
    out_proj<<<dim3(RNN_T * RNN_B / 4), dim3(256), 0, stream>>>(Wo, out_h, out_o);
}